// Round 16
// baseline (155.478 us; speedup 1.0000x reference)
//
#include <hip/hip_runtime.h>
#include <hip/hip_bf16.h>

typedef __attribute__((ext_vector_type(8))) short bf16x8;
typedef __attribute__((ext_vector_type(4))) float f32x4;

#define B    4
#define CIN  128
#define COUT 256
#define H    256
#define W    256
#define HW   (H * W)
#define ROWS 8           // rows per block (4 pairs)
#define PXW  64          // px strip per block

__device__ __forceinline__ unsigned short f2bf(float f) {
  unsigned int u = __builtin_bit_cast(unsigned int, f);
  u += 0x7fff + ((u >> 16) & 1);
  return (unsigned short)(u >> 16);
}

__global__ void cvt_wpw(const float* __restrict__ w, unsigned short* __restrict__ o) {
  int i = blockIdx.x * 256 + threadIdx.x;
  if (i < COUT * CIN) o[i] = f2bf(w[i]);
}

struct Row { float L; f32x4 a; f32x4 b; float R; };

__device__ __forceinline__ float rget(const Row& r, int j) {
  return (j < 0) ? r.L : (j < 4) ? r.a[j & 3] : (j < 8) ? r.b[j & 3] : r.R;
}

__device__ __forceinline__ Row load_row(const float* xr, int px0, bool pL, bool pR) {
  Row r;
  r.a = *(const f32x4*)(xr + px0);
  r.b = *(const f32x4*)(xr + px0 + 4);
  r.L = pL ? xr[px0 - 1] : 0.f;
  r.R = pR ? xr[px0 + 8] : 0.f;
  return r;
}

__device__ __forceinline__ Row zero_row() {
  Row r; r.L = r.R = 0.f;
  r.a = (f32x4){0.f,0.f,0.f,0.f};
  r.b = (f32x4){0.f,0.f,0.f,0.f};
  return r;
}

// Pair-buffer layout: byte = buf*32768 + rr*16384 + pxl*256 + ci*2.
// swz exactly as R8/R12: dw u16 writes 2 lanes/bank (free), b128 reads balanced.
__device__ __forceinline__ unsigned swz(unsigned La) {
  unsigned g = ((La >> 8) & 7) ^ ((La >> 11) & 7);
  return La ^ (g << 4);
}

// ---------------------------------------------------------------------------
// R16 = R15 pipeline with the spill cause removed.
// R15 counters: VGPR=64 + ~110MB scratch writes. Cause: 64KB LDS made
// 2 blocks/CU feasible -> compiler capped VGPR at 64 -> spill. Fix: pad LDS
// to 96KB (only 64KB used) -> 1 block/CU -> VGPR cap 128 -> pipeline
// liveness (~100 regs) fits. Structure unchanged (validated: absmax 0.03125):
// per step: prefetch x rows (k+1) -> GEMM+f32x4-stores(pair k-1) -> dw(pair k)
// -> lgkmcnt(0) + raw s_barrier (stores never drained inside the loop).
// ---------------------------------------------------------------------------
__global__ __launch_bounds__(1024, 4) void fused_kernel(
    const float* __restrict__ x, const float* __restrict__ wdw,
    const unsigned short* __restrict__ wb, float* __restrict__ out)
{
  int bid = blockIdx.x;
  int xcd = bid & 7;
  int k   = bid >> 3;          // 0..63
  int hcl = k & 3;
  int s   = (k >> 2) & 3;      // 4 strips of 64 px
  int b   = k >> 4;            // 0..3
  int hc  = xcd * 4 + hcl;     // 0..31
  int hBase = hc * ROWS;       // 0..248

  int t = threadIdx.x;
  int ci  = t >> 3;            // 0..127
  int pxg = t & 7;             // 0..7, 8 px each
  int px0 = s * PXW + pxg * 8;
  bool pL = px0 > 0, pR = px0 + 8 < W;

  // 96 KB: 2 x 32 KB live pair-buffers + 32 KB PAD. The pad forbids a second
  // resident block (96*2 > 160KB), so the compiler's occupancy target is
  // 16 waves/CU -> VGPR cap 128 -> no spill (R15's failure mode).
  __shared__ __align__(16) char yb[3 * 32768];

  float wr[9];
#pragma unroll
  for (int q = 0; q < 9; ++q) wr[q] = wdw[ci * 9 + q];

  const float* xc = x + ((size_t)b * CIN + ci) * HW;

  // GEMM ids (R13-verified swapped mapping: D[px][co])
  int wave = t >> 6, l = t & 63;
  int l15 = l & 15, lg = l >> 4;
  int coBase = wave * 16;      // 16 waves x 16 co = 256

  bf16x8 Wf[4];
#pragma unroll
  for (int kk = 0; kk < 4; ++kk)
    Wf[kk] = *(const bf16x8*)(wb + (coBase + l15) * CIN + kk * 32 + lg * 8);

  auto dw_row = [&](char* buf, int rr, const Row& Ra, const Row& Rb, const Row& Rc) {
#pragma unroll
    for (int j = 0; j < 8; ++j) {
      float a =
        rget(Ra, j-1)*wr[0] + rget(Ra, j)*wr[1] + rget(Ra, j+1)*wr[2] +
        rget(Rb, j-1)*wr[3] + rget(Rb, j)*wr[4] + rget(Rb, j+1)*wr[5] +
        rget(Rc, j-1)*wr[6] + rget(Rc, j)*wr[7] + rget(Rc, j+1)*wr[8];
      unsigned La = (unsigned)rr * 16384u + (unsigned)(pxg * 8 + j) * 256u + (unsigned)ci * 2u;
      *(unsigned short*)(buf + swz(La)) = f2bf(a);
    }
  };

  auto gemm_pair = [&](const char* buf, int p) {
    float* ob = out + (size_t)b * COUT * HW + s * PXW;
#pragma unroll
    for (int rr = 0; rr < 2; ++rr) {
      int h = hBase + p * 2 + rr;
      float* orow = ob + (size_t)h * W + (size_t)(coBase + l15) * HW;
#pragma unroll
      for (int m = 0; m < 4; ++m) {
        bf16x8 Yf[4];
#pragma unroll
        for (int kk = 0; kk < 4; ++kk) {
          unsigned La = (unsigned)rr * 16384u + (unsigned)(m * 16 + l15) * 256u
                      + (unsigned)(kk * 32 + lg * 8) * 2u;
          Yf[kk] = *(const bf16x8*)(buf + swz(La));
        }
        f32x4 acc = (f32x4){0.f,0.f,0.f,0.f};
#pragma unroll
        for (int kk = 0; kk < 4; ++kk)
          acc = __builtin_amdgcn_mfma_f32_16x16x32_bf16(Yf[kk], Wf[kk], acc, 0, 0, 0);
        *(f32x4*)(orow + m * 16 + lg * 4) = acc;   // px=m*16+lg*4+q, co=coBase+l15
      }
    }
  };

  // ---- prologue: rows hBase-1..hBase+4 ----
  Row A  = (hBase > 0) ? load_row(xc + (size_t)(hBase - 1) * W, px0, pL, pR) : zero_row();
  Row Bv = load_row(xc + (size_t)(hBase + 0) * W, px0, pL, pR);
  Row C  = load_row(xc + (size_t)(hBase + 1) * W, px0, pL, pR);
  Row D  = load_row(xc + (size_t)(hBase + 2) * W, px0, pL, pR);
  Row C2 = load_row(xc + (size_t)(hBase + 3) * W, px0, pL, pR);
  Row D2 = load_row(xc + (size_t)(hBase + 4) * W, px0, pL, pR);

  dw_row(yb, 0, A, Bv, C);
  dw_row(yb, 1, Bv, C, D);
  asm volatile("s_waitcnt lgkmcnt(0)" ::: "memory");
  __builtin_amdgcn_s_barrier();

#pragma unroll
  for (int kp = 1; kp < 4; ++kp) {
    A = C; Bv = D; C = C2; D = D2;
    if (kp < 3) {
      int hh = hBase + 2 * kp + 3;
      bool ok = (hh + 1) < H;            // block-uniform; false only at bottom
      C2 = load_row(xc + (size_t)hh * W, px0, pL, pR);       // hh <= 255 valid
      D2 = ok ? load_row(xc + (size_t)(hh + 1) * W, px0, pL, pR) : zero_row();
    }
    char* wbuf = yb + (kp & 1) * 32768;
    const char* rbuf = yb + ((kp - 1) & 1) * 32768;

    gemm_pair(rbuf, kp - 1);             // stores fire-and-forget
    dw_row(wbuf, 0, A, Bv, C);           // pair kp rows
    dw_row(wbuf, 1, Bv, C, D);
    asm volatile("s_waitcnt lgkmcnt(0)" ::: "memory");
    __builtin_amdgcn_s_barrier();        // NO vmcnt: stores stay in flight
  }

  gemm_pair(yb + 32768, 3);              // final pair (buf1)
}

extern "C" void kernel_launch(void* const* d_in, const int* in_sizes, int n_in,
                              void* d_out, int out_size, void* d_ws, size_t ws_size,
                              hipStream_t stream) {
  const float* x   = (const float*)d_in[0];
  const float* wdw = (const float*)d_in[1];
  const float* wpw = (const float*)d_in[2];
  float* out = (float*)d_out;

  unsigned short* wbb = (unsigned short*)d_ws;   // 64 KB bf16 pw weights

  cvt_wpw<<<(COUT * CIN + 255) / 256, 256, 0, stream>>>(wpw, wbb);
  fused_kernel<<<B * (H / ROWS) * (W / PXW), 1024, 0, stream>>>(x, wdw, wbb, out);
}